// Round 1
// baseline (1457.107 us; speedup 1.0000x reference)
//
#include <hip/hip_runtime.h>

namespace {
constexpr int N_NODES = 50000;
constexpr int N_EDGES = 400000;
constexpr int MUL0 = 16;
constexpr int MUL1 = 8;
constexpr int DIM  = MUL0 + 3 * MUL1;   // 40
constexpr int RMLP = 64;
constexpr int WNUM = MUL0*MUL0 + MUL1*MUL0 + MUL0*MUL1 + MUL1*MUL1;  // 576
constexpr float C_N0 = 0.2041241452319315f;        // sqrt(1/24)
constexpr float C_N1 = 0.3535533905932738f;        // sqrt(3/24)
constexpr float C_INV_SQRT3 = 0.5773502691896258f;
constexpr float C_SQRT3 = 1.7320508075688772f;
}

// w2t[j*64 + r] = w2[r*576 + j]  (column-major copy so each output j's 64
// weights are contiguous -> s_load_dwordx16 friendly)
__global__ __launch_bounds__(256) void transpose_w2(
    const float* __restrict__ w2, float* __restrict__ w2t)
{
    int idx = blockIdx.x * 256 + threadIdx.x;
    if (idx >= RMLP * WNUM) return;
    int j = idx >> 6;          // 0..575
    int r = idx & 63;          // 0..63
    w2t[idx] = w2[r * WNUM + j];
}

__global__ __launch_bounds__(256) void edge_kernel(
    const float* __restrict__ h,
    const int*   __restrict__ ei,
    const float* __restrict__ evec,
    const float* __restrict__ elen,
    const float* __restrict__ w1,
    const float* __restrict__ b1,
    const float* __restrict__ w2t,   // [576][64]
    const float* __restrict__ b2,
    float*       __restrict__ agg)   // d_out, pre-zeroed; atomic accumulate
{
    const int e = blockIdx.x * 256 + threadIdx.x;
    if (e >= N_EDGES) return;

    const int snd = ei[e];
    const int rcv = ei[N_EDGES + e];

    const float v0 = evec[3*e+0], v1 = evec[3*e+1], v2 = evec[3*e+2];
    const float rinv = rsqrtf(v0*v0 + v1*v1 + v2*v2) * C_SQRT3;
    const float s0 = v0 * rinv, s1 = v1 * rinv, s2 = v2 * rinv;  // sh1

    // radial MLP hidden activations (uniform weights -> scalar loads)
    const float len = elen[e];
    float act[RMLP];
#pragma unroll
    for (int r = 0; r < RMLP; ++r) {
        const float t = fmaf(len, w1[r], b1[r]);
        act[r] = t / (1.0f + __expf(-t));     // silu
    }

    // gathered sender features
    const float* hp = h + (long)snd * DIM;
    float hs[MUL0], hv[3*MUL1];
#pragma unroll
    for (int u = 0; u < MUL0; ++u) hs[u] = hp[u];
#pragma unroll
    for (int i = 0; i < 3*MUL1; ++i) hv[i] = hp[MUL0 + i];

    float dotc[MUL1];   // INV_SQRT3 * (hv[u] . sh1)
#pragma unroll
    for (int u = 0; u < MUL1; ++u)
        dotc[u] = C_INV_SQRT3 *
            (hv[3*u]*s0 + hv[3*u+1]*s1 + hv[3*u+2]*s2);

    float outs[MUL0] = {};     // out_s / N0
    float t3[MUL1]   = {};     // hs . W3
    float outv[3*MUL1] = {};   // t4

    // ---- region 1: W1, j = u*16 + w, outs[w] += hs[u]*wj ----
#pragma unroll 1
    for (int u = 0; u < MUL0; ++u) {
        const float hu = hs[u];
#pragma unroll 2
        for (int w = 0; w < MUL0; ++w) {
            const int j = u*MUL0 + w;
            float wj = b2[j];
            const float* col = w2t + j*RMLP;
#pragma unroll
            for (int r = 0; r < RMLP; ++r) wj = fmaf(act[r], col[r], wj);
            outs[w] = fmaf(hu, wj, outs[w]);
        }
    }
    // ---- region 2: W2, j = 256 + u*16 + w, outs[w] += dotc[u]*wj ----
#pragma unroll 1
    for (int u = 0; u < MUL1; ++u) {
        const float du = dotc[u];
#pragma unroll 2
        for (int w = 0; w < MUL0; ++w) {
            const int j = MUL0*MUL0 + u*MUL0 + w;
            float wj = b2[j];
            const float* col = w2t + j*RMLP;
#pragma unroll
            for (int r = 0; r < RMLP; ++r) wj = fmaf(act[r], col[r], wj);
            outs[w] = fmaf(du, wj, outs[w]);
        }
    }
    // ---- region 3: W3, j = 384 + u*8 + w, t3[w] += hs[u]*wj ----
#pragma unroll 1
    for (int u = 0; u < MUL0; ++u) {
        const float hu = hs[u];
#pragma unroll 2
        for (int w = 0; w < MUL1; ++w) {
            const int j = MUL0*MUL0 + MUL1*MUL0 + u*MUL1 + w;
            float wj = b2[j];
            const float* col = w2t + j*RMLP;
#pragma unroll
            for (int r = 0; r < RMLP; ++r) wj = fmaf(act[r], col[r], wj);
            t3[w] = fmaf(hu, wj, t3[w]);
        }
    }
    // ---- region 4: W4, j = 512 + u*8 + w, outv[3w+k] += hv[3u+k]*wj ----
#pragma unroll 1
    for (int u = 0; u < MUL1; ++u) {
#pragma unroll 2
        for (int w = 0; w < MUL1; ++w) {
            const int j = MUL0*MUL0 + 2*MUL1*MUL0 + u*MUL1 + w;
            float wj = b2[j];
            const float* col = w2t + j*RMLP;
#pragma unroll
            for (int r = 0; r < RMLP; ++r) wj = fmaf(act[r], col[r], wj);
            outv[3*w+0] = fmaf(hv[3*u+0], wj, outv[3*w+0]);
            outv[3*w+1] = fmaf(hv[3*u+1], wj, outv[3*w+1]);
            outv[3*w+2] = fmaf(hv[3*u+2], wj, outv[3*w+2]);
        }
    }

    float* ag = agg + (long)rcv * DIM;
#pragma unroll
    for (int w = 0; w < MUL0; ++w)
        unsafeAtomicAdd(ag + w, C_N0 * outs[w]);
    const float nv = C_N1 * C_INV_SQRT3;
#pragma unroll
    for (int w = 0; w < MUL1; ++w) {
        unsafeAtomicAdd(ag + MUL0 + 3*w + 0, nv * fmaf(t3[w], s0, outv[3*w+0]));
        unsafeAtomicAdd(ag + MUL0 + 3*w + 1, nv * fmaf(t3[w], s1, outv[3*w+1]));
        unsafeAtomicAdd(ag + MUL0 + 3*w + 2, nv * fmaf(t3[w], s2, outv[3*w+2]));
    }
}

// out currently holds agg; apply gate + residual in-place.
__global__ __launch_bounds__(256) void node_kernel(
    const float* __restrict__ h,
    const float* __restrict__ gw,   // [16][24]
    const float* __restrict__ gb,   // [24]
    float*       __restrict__ out)
{
    const int n = blockIdx.x * 256 + threadIdx.x;
    if (n >= N_NODES) return;
    const float* hp = h + (long)n * DIM;
    float* op = out + (long)n * DIM;

    float hsv[MUL0];
#pragma unroll
    for (int u = 0; u < MUL0; ++u) hsv[u] = hp[u];
    float ag[DIM];
#pragma unroll
    for (int i = 0; i < DIM; ++i) ag[i] = op[i];

#pragma unroll
    for (int i = 0; i < MUL0; ++i) op[i] = hsv[i] + ag[i];

#pragma unroll 1
    for (int j = 0; j < 3*MUL1; ++j) {
        float a = gb[j];
#pragma unroll
        for (int u = 0; u < MUL0; ++u) a = fmaf(hsv[u], gw[u*(3*MUL1) + j], a);
        const float g = 1.0f / (1.0f + __expf(-a));
        op[MUL0 + j] = fmaf(ag[MUL0 + j], g, hp[MUL0 + j]);
    }
}

extern "C" void kernel_launch(void* const* d_in, const int* in_sizes, int n_in,
                              void* d_out, int out_size, void* d_ws, size_t ws_size,
                              hipStream_t stream)
{
    const float* h    = (const float*)d_in[0];
    const int*   ei   = (const int*)d_in[1];
    const float* evec = (const float*)d_in[2];
    const float* elen = (const float*)d_in[3];
    const float* w1   = (const float*)d_in[4];
    const float* b1   = (const float*)d_in[5];
    const float* w2   = (const float*)d_in[6];
    const float* b2   = (const float*)d_in[7];
    const float* gw   = (const float*)d_in[8];
    const float* gb   = (const float*)d_in[9];
    float* out = (float*)d_out;
    float* w2t = (float*)d_ws;   // 576*64 f32 = 147456 B

    hipMemsetAsync(d_out, 0, (size_t)out_size * sizeof(float), stream);
    transpose_w2<<<(RMLP*WNUM + 255)/256, 256, 0, stream>>>(w2, w2t);
    edge_kernel<<<(N_EDGES + 255)/256, 256, 0, stream>>>(
        h, ei, evec, elen, w1, b1, w2t, b2, out);
    node_kernel<<<(N_NODES + 255)/256, 256, 0, stream>>>(h, gw, gb, out);
}

// Round 4
// 991.866 us; speedup vs baseline: 1.4691x; 1.4691x over previous
//
#include <hip/hip_runtime.h>

typedef _Float16 half8  __attribute__((ext_vector_type(8)));
typedef _Float16 half4v __attribute__((ext_vector_type(4)));
typedef float    float4v __attribute__((ext_vector_type(4)));

namespace {
constexpr int N_NODES = 50000;
constexpr int N_EDGES = 400000;
constexpr int MUL0 = 16;
constexpr int MUL1 = 8;
constexpr int DIM  = 40;
constexpr int RMLP = 64;
constexpr int WNUM = 576;
constexpr int EB    = 64;    // edges per block
constexpr int CHUNK = 144;   // j-columns per chunk (4 chunks of 576)
constexpr float C_N0 = 0.2041241452319315f;        // sqrt(1/24)
constexpr float C_N1 = 0.3535533905932738f;        // sqrt(3/24)
constexpr float C_INV3 = 0.5773502691896258f;      // 1/sqrt(3)
constexpr float C_SQRT3 = 1.7320508075688772f;
}

// Fused: per block, 64 edges. Phases per j-chunk (144 cols):
//   [load w2 chunk f16->LDS] SYNC [MFMA act@w2 -> wstg(LDS,f16)] SYNC [contraction]
// Slice s = tid>>6 owns all j == s (mod 8); every einsum's output index w
// satisfies w == j (mod 8), so slices never need cross-thread reduction.
__global__ __launch_bounds__(512) void edge_fused(
    const float* __restrict__ h,
    const int*   __restrict__ ei,
    const float* __restrict__ evec,
    const float* __restrict__ elen,
    const float* __restrict__ w1,
    const float* __restrict__ b1,
    const float* __restrict__ w2,
    const float* __restrict__ b2,
    float*       __restrict__ agg)   // d_out, pre-zeroed
{
    __shared__ __align__(16) _Float16 actL[64][72];   // [edge][r] (+8 pad)
    __shared__ __align__(16) _Float16 w2L[CHUNK][72]; // [j][r]   (+8 pad)
    __shared__ __align__(16) _Float16 wstg[CHUNK][72];// [j][edge](+8 pad)
    __shared__ float featL[64][53];  // [0:16)=hs [16:40)=hv [40:48)=dotc [48:51)=sh1

    const int t = threadIdx.x;
    const int ebase = blockIdx.x * EB;

    // ---------------- phase 0: features + act ----------------
    {
        const int e  = t >> 3;
        const int r8 = t & 7;
        const int snd = ei[ebase + e];
        const float* hp = h + (long)snd * DIM;
        if (r8 == 0) {
            const float v0 = evec[3*(ebase+e)+0];
            const float v1 = evec[3*(ebase+e)+1];
            const float v2 = evec[3*(ebase+e)+2];
            const float rinv = rsqrtf(v0*v0 + v1*v1 + v2*v2) * C_SQRT3;
            featL[e][48] = v0*rinv; featL[e][49] = v1*rinv; featL[e][50] = v2*rinv;
        }
#pragma unroll
        for (int q = 0; q < 5; ++q) {
            const int idx = r8*5 + q;           // covers 0..39
            featL[e][idx] = hp[idx];
        }
        __syncthreads();
        {   // dotc[u] = INV3 * (hv[u] . sh1), u = r8
            const int u = r8;
            const float s0 = featL[e][48], s1 = featL[e][49], s2 = featL[e][50];
            const float d = featL[e][16+3*u+0]*s0 + featL[e][16+3*u+1]*s1
                          + featL[e][16+3*u+2]*s2;
            featL[e][40+u] = C_INV3 * d;
        }
        {   // act: 8 silu values per thread -> f16 LDS
            const float len = elen[ebase + e];
            const int r0 = r8 * 8;
            half8 av;
#pragma unroll
            for (int q = 0; q < 8; ++q) {
                const float tv = fmaf(len, w1[r0+q], b1[r0+q]);
                av[q] = (_Float16)(tv / (1.0f + __expf(-tv)));
            }
            *(half8*)&actL[e][r0] = av;
        }
    }
    // (no extra sync: first SYNC1 below orders actL/featL writes vs MFMA reads)

    const int wid  = t >> 6;
    const int lane = t & 63;
    const int l15  = lane & 15;
    const int lg   = lane >> 4;
    const int ce = t & 63;   // contraction: edge
    const int s  = t >> 6;   // contraction: slice (j mod 8)

    float os0 = 0.f, os1 = 0.f, tt3 = 0.f, vv0 = 0.f, vv1 = 0.f, vv2 = 0.f;

#pragma unroll 4
    for (int c = 0; c < 4; ++c) {
        const int cbase = c * CHUNK;
        // ---- load w2 chunk: w2L[j][r] = w2[r][cbase+j], coalesced on j ----
#pragma unroll
        for (int k = 0; k < 18; ++k) {
            const int idx = t + k*512;          // 0..9215
            const int j = idx % CHUNK;
            const int r = idx / CHUNK;
            w2L[j][r] = (_Float16)w2[r*WNUM + cbase + j];
        }
        __syncthreads();   // SYNC1: w2L ready; prev contraction done (wstg safe)

        // ---- MFMA: 36 16x16 tiles (4 e-tiles x 9 j-tiles), K=64 ----
        for (int tt = wid; tt < 36; tt += 8) {
            const int et = tt / 9;
            const int jt = tt - et*9;
            const half8 a0 = *(const half8*)&actL[et*16 + l15][lg*8];
            const half8 a1 = *(const half8*)&actL[et*16 + l15][32 + lg*8];
            const half8 b0 = *(const half8*)&w2L[jt*16 + l15][lg*8];
            const half8 b1 = *(const half8*)&w2L[jt*16 + l15][32 + lg*8];
            float4v acc = {0.f, 0.f, 0.f, 0.f};
            acc = __builtin_amdgcn_mfma_f32_16x16x32_f16(a0, b0, acc, 0, 0, 0);
            acc = __builtin_amdgcn_mfma_f32_16x16x32_f16(a1, b1, acc, 0, 0, 0);
            const float b2v = b2[cbase + jt*16 + l15];
            half4v o;
#pragma unroll
            for (int r = 0; r < 4; ++r) o[r] = (_Float16)(acc[r] + b2v);
            // D layout: col(j)=lane&15, row(e)=(lane>>4)*4+reg  [guide m89]
            *(half4v*)&wstg[jt*16 + l15][et*16 + lg*4] = o;
        }
        __syncthreads();   // SYNC2: wstg ready

        // ---- contraction: slice s handles j_local = 8i+s, i in [0,18) ----
        if (c == 0) {          // j 0..143: region1, u=i>>1, w=(i&1)*8+s
#pragma unroll
            for (int i = 0; i < 18; ++i) {
                const float wv = (float)wstg[8*i + s][ce];
                const float f = featL[ce][i >> 1];           // hs[u]
                if (i & 1) os1 = fmaf(f, wv, os1); else os0 = fmaf(f, wv, os0);
            }
        } else if (c == 1) {   // j 144..287
#pragma unroll
            for (int i = 0; i < 14; ++i) {   // region1, u = 9+(i>>1)
                const float wv = (float)wstg[8*i + s][ce];
                const float f = featL[ce][9 + (i >> 1)];
                if (i & 1) os1 = fmaf(f, wv, os1); else os0 = fmaf(f, wv, os0);
            }
#pragma unroll
            for (int i = 14; i < 18; ++i) {  // region2, u = (i-14)>>1 (dotc)
                const float wv = (float)wstg[8*i + s][ce];
                const float f = featL[ce][40 + ((i-14) >> 1)];
                if (i & 1) os1 = fmaf(f, wv, os1); else os0 = fmaf(f, wv, os0);
            }
        } else if (c == 2) {   // j 288..431
#pragma unroll
            for (int i = 0; i < 12; ++i) {   // region2, u = 2+(i>>1) (dotc)
                const float wv = (float)wstg[8*i + s][ce];
                const float f = featL[ce][42 + (i >> 1)];
                if (i & 1) os1 = fmaf(f, wv, os1); else os0 = fmaf(f, wv, os0);
            }
#pragma unroll
            for (int i = 12; i < 18; ++i) {  // region3, u = i-12: t3
                const float wv = (float)wstg[8*i + s][ce];
                const float f = featL[ce][i - 12];           // hs[u]
                tt3 = fmaf(f, wv, tt3);
            }
        } else {               // j 432..575
#pragma unroll
            for (int i = 0; i < 10; ++i) {   // region3, u = 6+i: t3
                const float wv = (float)wstg[8*i + s][ce];
                const float f = featL[ce][6 + i];
                tt3 = fmaf(f, wv, tt3);
            }
#pragma unroll
            for (int i = 10; i < 18; ++i) {  // region4, u = i-10: t4
                const float wv = (float)wstg[8*i + s][ce];
                const int b = 16 + 3*(i - 10);
                vv0 = fmaf(featL[ce][b+0], wv, vv0);
                vv1 = fmaf(featL[ce][b+1], wv, vv1);
                vv2 = fmaf(featL[ce][b+2], wv, vv2);
            }
        }
        // no sync here: next chunk's SYNC1 orders wstg reads vs next writes
    }

    // ---------------- final: atomic scatter to agg ----------------
    {
        const int rcv = ei[N_EDGES + ebase + ce];
        float* ag = agg + (long)rcv * DIM;
        unsafeAtomicAdd(ag + s,     C_N0 * os0);
        unsafeAtomicAdd(ag + s + 8, C_N0 * os1);
        const float nv = C_N1 * C_INV3;
        const float s0 = featL[ce][48], s1 = featL[ce][49], s2 = featL[ce][50];
        unsafeAtomicAdd(ag + MUL0 + 3*s + 0, nv * fmaf(tt3, s0, vv0));
        unsafeAtomicAdd(ag + MUL0 + 3*s + 1, nv * fmaf(tt3, s1, vv1));
        unsafeAtomicAdd(ag + MUL0 + 3*s + 2, nv * fmaf(tt3, s2, vv2));
    }
}

// out currently holds agg; apply gate + residual in-place.
__global__ __launch_bounds__(256) void node_kernel(
    const float* __restrict__ h,
    const float* __restrict__ gw,   // [16][24]
    const float* __restrict__ gb,   // [24]
    float*       __restrict__ out)
{
    const int n = blockIdx.x * 256 + threadIdx.x;
    if (n >= N_NODES) return;
    const float* hp = h + (long)n * DIM;
    float* op = out + (long)n * DIM;

    float hsv[MUL0];
#pragma unroll
    for (int u = 0; u < MUL0; ++u) hsv[u] = hp[u];
    float ag[DIM];
#pragma unroll
    for (int i = 0; i < DIM; ++i) ag[i] = op[i];

#pragma unroll
    for (int i = 0; i < MUL0; ++i) op[i] = hsv[i] + ag[i];

#pragma unroll 1
    for (int j = 0; j < 3*MUL1; ++j) {
        float a = gb[j];
#pragma unroll
        for (int u = 0; u < MUL0; ++u) a = fmaf(hsv[u], gw[u*(3*MUL1) + j], a);
        const float g = 1.0f / (1.0f + __expf(-a));
        op[MUL0 + j] = fmaf(ag[MUL0 + j], g, hp[MUL0 + j]);
    }
}

extern "C" void kernel_launch(void* const* d_in, const int* in_sizes, int n_in,
                              void* d_out, int out_size, void* d_ws, size_t ws_size,
                              hipStream_t stream)
{
    const float* h    = (const float*)d_in[0];
    const int*   ei   = (const int*)d_in[1];
    const float* evec = (const float*)d_in[2];
    const float* elen = (const float*)d_in[3];
    const float* w1   = (const float*)d_in[4];
    const float* b1   = (const float*)d_in[5];
    const float* w2   = (const float*)d_in[6];
    const float* b2   = (const float*)d_in[7];
    const float* gw   = (const float*)d_in[8];
    const float* gb   = (const float*)d_in[9];
    float* out = (float*)d_out;

    hipMemsetAsync(d_out, 0, (size_t)out_size * sizeof(float), stream);
    edge_fused<<<N_EDGES / EB, 512, 0, stream>>>(
        h, ei, evec, elen, w1, b1, w2, b2, out);
    node_kernel<<<(N_NODES + 255)/256, 256, 0, stream>>>(h, gw, gb, out);
}

// Round 8
// 765.590 us; speedup vs baseline: 1.9032x; 1.2956x over previous
//
#include <hip/hip_runtime.h>

typedef _Float16 half8  __attribute__((ext_vector_type(8)));
typedef _Float16 half2v __attribute__((ext_vector_type(2)));
typedef float    float4v __attribute__((ext_vector_type(4)));

namespace {
constexpr int N_NODES = 50000;
constexpr int N_EDGES = 400000;
constexpr int MUL0 = 16;
constexpr int MUL1 = 8;
constexpr int DIM  = 40;
constexpr int RMLP = 64;
constexpr int WNUM = 576;
constexpr int GE   = 256;                      // edges per group
constexpr int NGROUP = (N_EDGES + GE - 1) / GE; // 1563 (last group = 128)
constexpr int GRID = 256;                      // 1 block per CU
// LDS carve (bytes): w2L[576][80]f16 | actL[256][80]f16 | featL[256][56]f16 | rcvL[256]i32
constexpr int WST = 80, AST = 80, FST = 56;
constexpr int OFF_ACT  = 92160;
constexpr int OFF_FEAT = 133120;
constexpr int OFF_RCV  = 161792;
constexpr int LDS_BYTES = 162816;              // <= 163840 (160 KiB/CU, AITER precedent m243)
// feat row layout (f16): h[0..39] (hs 0..15, hv 16..39), sh1[40..42], pad, dot[44..51]
constexpr float C_N0 = 0.2041241452319315f;    // sqrt(1/24)
constexpr float C_NV = 0.3535533905932738f * 0.5773502691896258f; // N1*inv_sqrt3
constexpr float C_INV3 = 0.5773502691896258f;
constexpr float C_SQRT3 = 1.7320508075688772f;
}

#define MFMA16(a, b, c) __builtin_amdgcn_mfma_f32_16x16x32_f16((a), (b), (c), 0, 0, 0)

// Persistent fused edge kernel. Per block: stage w2 (f16) to LDS once; loop
// over 256-edge groups. Per group: P0a stage feats/act | P0b dot | MFMA phase:
// A = w2 j-tile, B = act e-tile -> D[j,e] (col e=lane&15, row j=(lane>>4)*4+reg);
// bias b2[j] enters as the MFMA C-initializer (broadcast across e columns);
// per-tile scale by feat (1 b16 read/lane) and accumulate in registers; atomic
// scatter at the end. 3 barriers per group.
__global__ __launch_bounds__(512, 1) void edge_fused2(
    const float* __restrict__ h,
    const int*   __restrict__ ei,
    const float* __restrict__ evec,
    const float* __restrict__ elen,
    const float* __restrict__ w1,
    const float* __restrict__ b1,
    const float* __restrict__ w2,
    const float* __restrict__ b2,
    float*       __restrict__ agg)   // d_out, pre-zeroed
{
    extern __shared__ char smem[];
    _Float16* w2L  = (_Float16*)smem;               // [576][80]
    _Float16* actL = (_Float16*)(smem + OFF_ACT);   // [256][80]
    _Float16* featL= (_Float16*)(smem + OFF_FEAT);  // [256][56]
    int*      rcvL = (int*)(smem + OFF_RCV);        // [256]

    const int t = threadIdx.x;

    // ---- stage w2 once per block (visibility: barriers before first MFMA) ----
    for (int i = t; i < RMLP * WNUM; i += 512) {
        const int r = i / WNUM;
        const int j = i - r * WNUM;
        w2L[j * WST + r] = (_Float16)w2[i];
    }

    const int lane = t & 63, wid = t >> 6;
    const int l15 = lane & 15, lg = lane >> 4;
    const int usel = lg >> 1;

    for (int g = blockIdx.x; g < NGROUP; g += GRID) {
        const int base = g * GE;
        const int cnt = (N_EDGES - base < GE) ? (N_EDGES - base) : GE;

        // ---------------- P0a: stage feats + act (2 thr/edge) ----------------
        {
            const int el = t >> 1, q = t & 1;
            _Float16* fr = featL + el * FST;
            if (el < cnt) {
                const int eg = base + el;
                const int snd = ei[eg];
                const float* hp = h + (long)snd * DIM;
#pragma unroll
                for (int i = 0; i < 20; ++i)
                    fr[q * 20 + i] = (_Float16)hp[q * 20 + i];
                if (q == 0) {
                    rcvL[el] = ei[N_EDGES + eg];
                    const float v0 = evec[3 * eg + 0];
                    const float v1 = evec[3 * eg + 1];
                    const float v2 = evec[3 * eg + 2];
                    const float rinv = rsqrtf(v0 * v0 + v1 * v1 + v2 * v2) * C_SQRT3;
                    fr[40] = (_Float16)(v0 * rinv);
                    fr[41] = (_Float16)(v1 * rinv);
                    fr[42] = (_Float16)(v2 * rinv);
                }
                const float len = elen[eg];
#pragma unroll
                for (int i = 0; i < 4; ++i) {
                    half8 av;
#pragma unroll
                    for (int j2 = 0; j2 < 8; ++j2) {
                        const int r = q * 32 + i * 8 + j2;
                        const float tv = fmaf(len, w1[r], b1[r]);
                        av[j2] = (_Float16)(tv / (1.0f + __expf(-tv)));
                    }
                    *(half8*)&actL[el * AST + q * 32 + i * 8] = av;
                }
            } else {
                const half8 z = {};
#pragma unroll
                for (int i = 0; i < 20; ++i) fr[q * 20 + i] = (_Float16)0.f;
                if (q == 0) {
                    rcvL[el] = 0;
                    fr[40] = fr[41] = fr[42] = (_Float16)0.f;
                }
#pragma unroll
                for (int i = 0; i < 4; ++i)
                    *(half8*)&actL[el * AST + q * 32 + i * 8] = z;
            }
        }
        __syncthreads();

        // ---------------- P0b: dot[u] = INV3 * (hv[u].sh1)  (4 u per thr) ----
        {
            const int el = t >> 1;
            const int ub = (t & 1) * 4;
            const _Float16* fr = featL + el * FST;
            const float s0 = (float)fr[40], s1 = (float)fr[41], s2 = (float)fr[42];
#pragma unroll
            for (int j2 = 0; j2 < 4; ++j2) {
                const int u = ub + j2;
                const float d = (float)fr[16 + 3 * u + 0] * s0
                              + (float)fr[16 + 3 * u + 1] * s1
                              + (float)fr[16 + 3 * u + 2] * s2;
                featL[el * FST + 44 + u] = (_Float16)(C_INV3 * d);
            }
        }
        __syncthreads();

        // ---------------- MFMA + in-register contraction ----------------
        {
            const int et0 = wid * 2;   // this wave's 2 e-tiles (16 edges each)
            // B-frags (act), hoisted: lane holds B[k=lg*8+q][n=l15]
            half8 B[2][2];
#pragma unroll
            for (int tt = 0; tt < 2; ++tt)
#pragma unroll
                for (int s = 0; s < 2; ++s)
                    B[tt][s] = *(const half8*)&actL[((et0 + tt) * 16 + l15) * AST + s * 32 + lg * 8];

            const float4v zz = {0.f, 0.f, 0.f, 0.f};
            float4v os0 = zz, os1 = zz;
            float4v t30 = zz, t31 = zz;
            float4v t4a0 = zz, t4a1 = zz, t4a2 = zz;   // tile0, k=0..2
            float4v t4b0 = zz, t4b1 = zz, t4b2 = zz;   // tile1

            const _Float16* fA = featL + ((et0 + 0) * 16 + l15) * FST;
            const _Float16* fB = featL + ((et0 + 1) * 16 + l15) * FST;

            // ---- region 1: jt 0..15, u=jt, os += hs[u]*D ----
#pragma unroll
            for (int jp = 0; jp < 8; ++jp) {
                const half2v hA = *(const half2v*)&fA[2 * jp];
                const half2v hB = *(const half2v*)&fB[2 * jp];
#pragma unroll
                for (int h2 = 0; h2 < 2; ++h2) {
                    const int jt = 2 * jp + h2;
                    const float4v binit = *(const float4v*)&b2[jt * 16 + lg * 4];
                    const _Float16* wr = &w2L[(jt * 16 + l15) * WST];
                    const half8 w0 = *(const half8*)&wr[lg * 8];
                    const half8 w1v = *(const half8*)&wr[32 + lg * 8];
                    float4v d0 = MFMA16(w0, B[0][0], binit); d0 = MFMA16(w1v, B[0][1], d0);
                    float4v d1 = MFMA16(w0, B[1][0], binit); d1 = MFMA16(w1v, B[1][1], d1);
                    os0 += (float)hA[h2] * d0;
                    os1 += (float)hB[h2] * d1;
                }
            }
            // ---- region 2: jt 16..23, u=jt-16, os += dot[u]*D ----
#pragma unroll
            for (int jp = 0; jp < 4; ++jp) {
                const half2v hA = *(const half2v*)&fA[44 + 2 * jp];
                const half2v hB = *(const half2v*)&fB[44 + 2 * jp];
#pragma unroll
                for (int h2 = 0; h2 < 2; ++h2) {
                    const int jt = 16 + 2 * jp + h2;
                    const float4v binit = *(const float4v*)&b2[jt * 16 + lg * 4];
                    const _Float16* wr = &w2L[(jt * 16 + l15) * WST];
                    const half8 w0 = *(const half8*)&wr[lg * 8];
                    const half8 w1v = *(const half8*)&wr[32 + lg * 8];
                    float4v d0 = MFMA16(w0, B[0][0], binit); d0 = MFMA16(w1v, B[0][1], d0);
                    float4v d1 = MFMA16(w0, B[1][0], binit); d1 = MFMA16(w1v, B[1][1], d1);
                    os0 += (float)hA[h2] * d0;
                    os1 += (float)hB[h2] * d1;
                }
            }
            // ---- region 3: jt 24..31, u = 2*(jt-24)+usel, t3 += hs[u]*D ----
#pragma unroll
            for (int jt = 24; jt < 32; ++jt) {
                const int u = 2 * (jt - 24) + usel;
                const float4v binit = *(const float4v*)&b2[jt * 16 + lg * 4];
                const _Float16* wr = &w2L[(jt * 16 + l15) * WST];
                const half8 w0 = *(const half8*)&wr[lg * 8];
                const half8 w1v = *(const half8*)&wr[32 + lg * 8];
                float4v d0 = MFMA16(w0, B[0][0], binit); d0 = MFMA16(w1v, B[0][1], d0);
                float4v d1 = MFMA16(w0, B[1][0], binit); d1 = MFMA16(w1v, B[1][1], d1);
                t30 += (float)fA[u] * d0;
                t31 += (float)fB[u] * d1;
            }
            // ---- region 4: jt 32..35, u = 2*(jt-32)+usel, t4[k] += hv[u,k]*D ----
#pragma unroll
            for (int jt = 32; jt < 36; ++jt) {
                const int u = 2 * (jt - 32) + usel;
                const float4v binit = *(const float4v*)&b2[jt * 16 + lg * 4];
                const _Float16* wr = &w2L[(jt * 16 + l15) * WST];
                const half8 w0 = *(const half8*)&wr[lg * 8];
                const half8 w1v = *(const half8*)&wr[32 + lg * 8];
                float4v d0 = MFMA16(w0, B[0][0], binit); d0 = MFMA16(w1v, B[0][1], d0);
                float4v d1 = MFMA16(w0, B[1][0], binit); d1 = MFMA16(w1v, B[1][1], d1);
                t4a0 += (float)fA[16 + 3 * u + 0] * d0;
                t4a1 += (float)fA[16 + 3 * u + 1] * d0;
                t4a2 += (float)fA[16 + 3 * u + 2] * d0;
                t4b0 += (float)fB[16 + 3 * u + 0] * d1;
                t4b1 += (float)fB[16 + 3 * u + 1] * d1;
                t4b2 += (float)fB[16 + 3 * u + 2] * d1;
            }

            // combine lg-halves (lane^32 holds the partner-u partials; same edge, same w)
#pragma unroll
            for (int r = 0; r < 4; ++r) {
                t30[r] += __shfl_xor(t30[r], 32);
                t31[r] += __shfl_xor(t31[r], 32);
                t4a0[r] += __shfl_xor(t4a0[r], 32);
                t4a1[r] += __shfl_xor(t4a1[r], 32);
                t4a2[r] += __shfl_xor(t4a2[r], 32);
                t4b0[r] += __shfl_xor(t4b0[r], 32);
                t4b1[r] += __shfl_xor(t4b1[r], 32);
                t4b2[r] += __shfl_xor(t4b2[r], 32);
            }

            // ---- atomic scatter ----
#pragma unroll
            for (int tt = 0; tt < 2; ++tt) {
                const int el = (et0 + tt) * 16 + l15;
                if (el < cnt) {
                    const int rcv = rcvL[el];
                    float* ag = agg + (long)rcv * DIM;
                    const float4v& os = tt ? os1 : os0;
#pragma unroll
                    for (int r = 0; r < 4; ++r)
                        unsafeAtomicAdd(ag + lg * 4 + r, C_N0 * os[r]);
                    if (lg < 2) {
                        const _Float16* fr = featL + el * FST;
                        const float s0 = (float)fr[40], s1 = (float)fr[41], s2 = (float)fr[42];
                        const float4v& t3 = tt ? t31 : t30;
                        const float4v& v0 = tt ? t4b0 : t4a0;
                        const float4v& v1 = tt ? t4b1 : t4a1;
                        const float4v& v2 = tt ? t4b2 : t4a2;
#pragma unroll
                        for (int r = 0; r < 4; ++r) {
                            const int w = lg * 4 + r;   // 0..7
                            unsafeAtomicAdd(ag + 16 + 3 * w + 0, C_NV * (v0[r] + t3[r] * s0));
                            unsafeAtomicAdd(ag + 16 + 3 * w + 1, C_NV * (v1[r] + t3[r] * s1));
                            unsafeAtomicAdd(ag + 16 + 3 * w + 2, C_NV * (v2[r] + t3[r] * s2));
                        }
                    }
                }
            }
        }
        __syncthreads();   // protect actL/featL/rcvL before next group's P0a
    }
}

// out currently holds agg; apply gate + residual in-place.
__global__ __launch_bounds__(256) void node_kernel(
    const float* __restrict__ h,
    const float* __restrict__ gw,   // [16][24]
    const float* __restrict__ gb,   // [24]
    float*       __restrict__ out)
{
    const int n = blockIdx.x * 256 + threadIdx.x;
    if (n >= N_NODES) return;
    const float* hp = h + (long)n * DIM;
    float* op = out + (long)n * DIM;

    float hsv[MUL0];
#pragma unroll
    for (int u = 0; u < MUL0; ++u) hsv[u] = hp[u];
    float ag[DIM];
#pragma unroll
    for (int i = 0; i < DIM; ++i) ag[i] = op[i];

#pragma unroll
    for (int i = 0; i < MUL0; ++i) op[i] = hsv[i] + ag[i];

#pragma unroll 1
    for (int j = 0; j < 3 * MUL1; ++j) {
        float a = gb[j];
#pragma unroll
        for (int u = 0; u < MUL0; ++u) a = fmaf(hsv[u], gw[u * (3 * MUL1) + j], a);
        const float g = 1.0f / (1.0f + __expf(-a));
        op[MUL0 + j] = fmaf(ag[MUL0 + j], g, hp[MUL0 + j]);
    }
}

extern "C" void kernel_launch(void* const* d_in, const int* in_sizes, int n_in,
                              void* d_out, int out_size, void* d_ws, size_t ws_size,
                              hipStream_t stream)
{
    const float* h    = (const float*)d_in[0];
    const int*   ei   = (const int*)d_in[1];
    const float* evec = (const float*)d_in[2];
    const float* elen = (const float*)d_in[3];
    const float* w1   = (const float*)d_in[4];
    const float* b1   = (const float*)d_in[5];
    const float* w2   = (const float*)d_in[6];
    const float* b2   = (const float*)d_in[7];
    const float* gw   = (const float*)d_in[8];
    const float* gb   = (const float*)d_in[9];
    float* out = (float*)d_out;

    // Opt-in for >64KiB dynamic LDS where the runtime gates it (no-op otherwise;
    // host-side attribute set, graph-capture safe, identical work every call).
    (void)hipFuncSetAttribute((const void*)edge_fused2,
                              hipFuncAttributeMaxDynamicSharedMemorySize,
                              LDS_BYTES);

    hipMemsetAsync(d_out, 0, (size_t)out_size * sizeof(float), stream);
    edge_fused2<<<GRID, 512, LDS_BYTES, stream>>>(
        h, ei, evec, elen, w1, b1, w2, b2, out);
    node_kernel<<<(N_NODES + 255) / 256, 256, 0, stream>>>(h, gw, gb, out);
}

// Round 12
// 359.176 us; speedup vs baseline: 4.0568x; 2.1315x over previous
//
#include <hip/hip_runtime.h>
#include <hip/hip_fp16.h>

typedef _Float16 half8  __attribute__((ext_vector_type(8)));
typedef _Float16 half2v __attribute__((ext_vector_type(2)));
typedef float    float4v __attribute__((ext_vector_type(4)));

namespace {
constexpr int N_NODES = 50000;
constexpr int N_EDGES = 400000;
constexpr int MUL0 = 16;
constexpr int MUL1 = 8;
constexpr int DIM  = 40;
constexpr int RMLP = 64;
constexpr int WNUM = 576;
constexpr int GE   = 256;                      // edges per group
constexpr int NGROUP = (N_EDGES + GE - 1) / GE; // 1563 (last group = 128)
constexpr int GRID = 256;                      // 1 block per CU
// LDS carve (bytes): w2L[576][80]f16 | actL[256][80]f16 | featL[256][56]f16 | rcvL[256]i32
constexpr int WST = 80, AST = 80, FST = 56;
constexpr int OFF_ACT  = 92160;
constexpr int OFF_FEAT = 133120;
constexpr int OFF_RCV  = 161792;
constexpr int LDS_BYTES = 162816;              // <= 163840 (160 KiB/CU)
constexpr float C_N0 = 0.2041241452319315f;    // sqrt(1/24)
constexpr float C_NV = 0.3535533905932738f * 0.5773502691896258f; // N1*inv_sqrt3
constexpr float C_INV3 = 0.5773502691896258f;
constexpr float C_SQRT3 = 1.7320508075688772f;
}

#define MFMA16(a, b, c) __builtin_amdgcn_mfma_f32_16x16x32_f16((a), (b), (c), 0, 0, 0)

// packed-f16 atomic add: flat_atomic_pk_add_f16 on gfx940+; CAS fallback else.
__device__ inline void h2_atomic_add(__half2* addr, __half2 val) {
#if __has_builtin(__builtin_amdgcn_flat_atomic_fadd_v2f16)
    half2v v = *reinterpret_cast<half2v*>(&val);
    (void)__builtin_amdgcn_flat_atomic_fadd_v2f16(
        reinterpret_cast<half2v*>(addr), v);
#else
    unsigned int* ai = reinterpret_cast<unsigned int*>(addr);
    unsigned int old = *ai, assumed;
    do {
        assumed = old;
        __half2 cur = *reinterpret_cast<__half2*>(&assumed);
        __half2 sum = __hadd2(cur, val);
        unsigned int nv = *reinterpret_cast<unsigned int*>(&sum);
        old = atomicCAS(ai, assumed, nv);
    } while (old != assumed);
#endif
}

// v3: same persistent MFMA structure as v2, but the aggregation is a 4MB f16
// arena in d_ws updated with packed-f16 atomics (half the ops/bytes of v2's
// 40x f32), and the scatter is software-pipelined: payload is computed into
// registers before the group-end barrier and the atomics issue AFTER it,
// overlapping the next group's P0a gather latency.
__global__ __launch_bounds__(512, 1) void edge_fused3(
    const float* __restrict__ h,
    const int*   __restrict__ ei,
    const float* __restrict__ evec,
    const float* __restrict__ elen,
    const float* __restrict__ w1,
    const float* __restrict__ b1,
    const float* __restrict__ w2,
    const float* __restrict__ b2,
    __half2*     __restrict__ agg2)  // d_ws, pre-zeroed, [N_NODES][20] half2
{
    extern __shared__ char smem[];
    _Float16* w2L  = (_Float16*)smem;               // [576][80]
    _Float16* actL = (_Float16*)(smem + OFF_ACT);   // [256][80]
    _Float16* featL= (_Float16*)(smem + OFF_FEAT);  // [256][56]
    int*      rcvL = (int*)(smem + OFF_RCV);        // [256]

    const int t = threadIdx.x;

    // ---- stage w2 once per block ----
    for (int i = t; i < RMLP * WNUM; i += 512) {
        const int r = i / WNUM;
        const int j = i - r * WNUM;
        w2L[j * WST + r] = (_Float16)w2[i];
    }

    const int lane = t & 63, wid = t >> 6;
    const int l15 = lane & 15, lg = lane >> 4;
    const int usel = lg >> 1;

    // pipelined scatter payload (registers only, statically indexed)
    __half2 pOS[2][2];
    __half2 pV[2][6];
    int pR[2] = {0, 0};
    int pValid[2] = {0, 0};
    bool havePrev = false;

    for (int g = blockIdx.x; g < NGROUP; g += GRID) {
        // ---- scatter previous group's payload (overlaps P0a below) ----
        if (havePrev) {
#pragma unroll
            for (int tt = 0; tt < 2; ++tt) {
                if (pValid[tt]) {
                    __half2* a2 = agg2 + (long)pR[tt] * 20;
                    h2_atomic_add(a2 + lg * 2 + 0, pOS[tt][0]);
                    h2_atomic_add(a2 + lg * 2 + 1, pOS[tt][1]);
                    if (lg < 2) {
#pragma unroll
                        for (int r2 = 0; r2 < 6; ++r2)
                            h2_atomic_add(a2 + 8 + 6 * lg + r2, pV[tt][r2]);
                    }
                }
            }
        }

        const int base = g * GE;
        const int cnt = (N_EDGES - base < GE) ? (N_EDGES - base) : GE;

        // ---------------- P0a: stage feats + act (2 thr/edge) ----------------
        {
            const int el = t >> 1, q = t & 1;
            _Float16* fr = featL + el * FST;
            if (el < cnt) {
                const int eg = base + el;
                const int snd = ei[eg];
                const float* hp = h + (long)snd * DIM;
#pragma unroll
                for (int i = 0; i < 20; ++i)
                    fr[q * 20 + i] = (_Float16)hp[q * 20 + i];
                if (q == 0) {
                    rcvL[el] = ei[N_EDGES + eg];
                    const float v0 = evec[3 * eg + 0];
                    const float v1 = evec[3 * eg + 1];
                    const float v2 = evec[3 * eg + 2];
                    const float rinv = rsqrtf(v0 * v0 + v1 * v1 + v2 * v2) * C_SQRT3;
                    fr[40] = (_Float16)(v0 * rinv);
                    fr[41] = (_Float16)(v1 * rinv);
                    fr[42] = (_Float16)(v2 * rinv);
                }
                const float len = elen[eg];
#pragma unroll
                for (int i = 0; i < 4; ++i) {
                    half8 av;
#pragma unroll
                    for (int j2 = 0; j2 < 8; ++j2) {
                        const int r = q * 32 + i * 8 + j2;
                        const float tv = fmaf(len, w1[r], b1[r]);
                        av[j2] = (_Float16)(tv / (1.0f + __expf(-tv)));
                    }
                    *(half8*)&actL[el * AST + q * 32 + i * 8] = av;
                }
            } else {
                const half8 z = {};
#pragma unroll
                for (int i = 0; i < 20; ++i) fr[q * 20 + i] = (_Float16)0.f;
                if (q == 0) {
                    rcvL[el] = 0;
                    fr[40] = fr[41] = fr[42] = (_Float16)0.f;
                }
#pragma unroll
                for (int i = 0; i < 4; ++i)
                    *(half8*)&actL[el * AST + q * 32 + i * 8] = z;
            }
        }
        __syncthreads();

        // ---------------- P0b: dot[u] = INV3 * (hv[u].sh1) ----------------
        {
            const int el = t >> 1;
            const int ub = (t & 1) * 4;
            const _Float16* fr = featL + el * FST;
            const float s0 = (float)fr[40], s1 = (float)fr[41], s2 = (float)fr[42];
#pragma unroll
            for (int j2 = 0; j2 < 4; ++j2) {
                const int u = ub + j2;
                const float d = (float)fr[16 + 3 * u + 0] * s0
                              + (float)fr[16 + 3 * u + 1] * s1
                              + (float)fr[16 + 3 * u + 2] * s2;
                featL[el * FST + 44 + u] = (_Float16)(C_INV3 * d);
            }
        }
        __syncthreads();

        // ---------------- MFMA + in-register contraction ----------------
        {
            const int et0 = wid * 2;
            half8 B[2][2];
#pragma unroll
            for (int tt = 0; tt < 2; ++tt)
#pragma unroll
                for (int s = 0; s < 2; ++s)
                    B[tt][s] = *(const half8*)&actL[((et0 + tt) * 16 + l15) * AST + s * 32 + lg * 8];

            const float4v zz = {0.f, 0.f, 0.f, 0.f};
            float4v os0 = zz, os1 = zz;
            float4v t30 = zz, t31 = zz;
            float4v t4a0 = zz, t4a1 = zz, t4a2 = zz;
            float4v t4b0 = zz, t4b1 = zz, t4b2 = zz;

            const _Float16* fA = featL + ((et0 + 0) * 16 + l15) * FST;
            const _Float16* fB = featL + ((et0 + 1) * 16 + l15) * FST;

            // region 1: jt 0..15, os += hs[u]*D
#pragma unroll
            for (int jp = 0; jp < 8; ++jp) {
                const half2v hA = *(const half2v*)&fA[2 * jp];
                const half2v hB = *(const half2v*)&fB[2 * jp];
#pragma unroll
                for (int h2 = 0; h2 < 2; ++h2) {
                    const int jt = 2 * jp + h2;
                    const float4v binit = *(const float4v*)&b2[jt * 16 + lg * 4];
                    const _Float16* wr = &w2L[(jt * 16 + l15) * WST];
                    const half8 w0 = *(const half8*)&wr[lg * 8];
                    const half8 w1v = *(const half8*)&wr[32 + lg * 8];
                    float4v d0 = MFMA16(w0, B[0][0], binit); d0 = MFMA16(w1v, B[0][1], d0);
                    float4v d1 = MFMA16(w0, B[1][0], binit); d1 = MFMA16(w1v, B[1][1], d1);
                    os0 += (float)hA[h2] * d0;
                    os1 += (float)hB[h2] * d1;
                }
            }
            // region 2: jt 16..23, os += dot[u]*D
#pragma unroll
            for (int jp = 0; jp < 4; ++jp) {
                const half2v hA = *(const half2v*)&fA[44 + 2 * jp];
                const half2v hB = *(const half2v*)&fB[44 + 2 * jp];
#pragma unroll
                for (int h2 = 0; h2 < 2; ++h2) {
                    const int jt = 16 + 2 * jp + h2;
                    const float4v binit = *(const float4v*)&b2[jt * 16 + lg * 4];
                    const _Float16* wr = &w2L[(jt * 16 + l15) * WST];
                    const half8 w0 = *(const half8*)&wr[lg * 8];
                    const half8 w1v = *(const half8*)&wr[32 + lg * 8];
                    float4v d0 = MFMA16(w0, B[0][0], binit); d0 = MFMA16(w1v, B[0][1], d0);
                    float4v d1 = MFMA16(w0, B[1][0], binit); d1 = MFMA16(w1v, B[1][1], d1);
                    os0 += (float)hA[h2] * d0;
                    os1 += (float)hB[h2] * d1;
                }
            }
            // region 3: jt 24..31, t3 += hs[u]*D
#pragma unroll
            for (int jt = 24; jt < 32; ++jt) {
                const int u = 2 * (jt - 24) + usel;
                const float4v binit = *(const float4v*)&b2[jt * 16 + lg * 4];
                const _Float16* wr = &w2L[(jt * 16 + l15) * WST];
                const half8 w0 = *(const half8*)&wr[lg * 8];
                const half8 w1v = *(const half8*)&wr[32 + lg * 8];
                float4v d0 = MFMA16(w0, B[0][0], binit); d0 = MFMA16(w1v, B[0][1], d0);
                float4v d1 = MFMA16(w0, B[1][0], binit); d1 = MFMA16(w1v, B[1][1], d1);
                t30 += (float)fA[u] * d0;
                t31 += (float)fB[u] * d1;
            }
            // region 4: jt 32..35, t4[k] += hv[u,k]*D
#pragma unroll
            for (int jt = 32; jt < 36; ++jt) {
                const int u = 2 * (jt - 32) + usel;
                const float4v binit = *(const float4v*)&b2[jt * 16 + lg * 4];
                const _Float16* wr = &w2L[(jt * 16 + l15) * WST];
                const half8 w0 = *(const half8*)&wr[lg * 8];
                const half8 w1v = *(const half8*)&wr[32 + lg * 8];
                float4v d0 = MFMA16(w0, B[0][0], binit); d0 = MFMA16(w1v, B[0][1], d0);
                float4v d1 = MFMA16(w0, B[1][0], binit); d1 = MFMA16(w1v, B[1][1], d1);
                t4a0 += (float)fA[16 + 3 * u + 0] * d0;
                t4a1 += (float)fA[16 + 3 * u + 1] * d0;
                t4a2 += (float)fA[16 + 3 * u + 2] * d0;
                t4b0 += (float)fB[16 + 3 * u + 0] * d1;
                t4b1 += (float)fB[16 + 3 * u + 1] * d1;
                t4b2 += (float)fB[16 + 3 * u + 2] * d1;
            }

            // combine lg-halves (lane^32 holds the partner-u partials)
#pragma unroll
            for (int r = 0; r < 4; ++r) {
                t30[r] += __shfl_xor(t30[r], 32);
                t31[r] += __shfl_xor(t31[r], 32);
                t4a0[r] += __shfl_xor(t4a0[r], 32);
                t4a1[r] += __shfl_xor(t4a1[r], 32);
                t4a2[r] += __shfl_xor(t4a2[r], 32);
                t4b0[r] += __shfl_xor(t4b0[r], 32);
                t4b1[r] += __shfl_xor(t4b1[r], 32);
                t4b2[r] += __shfl_xor(t4b2[r], 32);
            }

            // ---- build scatter payload in registers (reads LDS pre-barrier) ----
#pragma unroll
            for (int tt = 0; tt < 2; ++tt) {
                const int el = (et0 + tt) * 16 + l15;
                pValid[tt] = (el < cnt);
                pR[tt] = rcvL[el];
                const float4v& os = tt ? os1 : os0;
                pOS[tt][0] = __floats2half2_rn(C_N0 * os[0], C_N0 * os[1]);
                pOS[tt][1] = __floats2half2_rn(C_N0 * os[2], C_N0 * os[3]);
                const _Float16* fr = featL + el * FST;
                const float s0 = (float)fr[40], s1 = (float)fr[41], s2 = (float)fr[42];
                const float4v& t3 = tt ? t31 : t30;
                const float4v& x0 = tt ? t4b0 : t4a0;
                const float4v& x1 = tt ? t4b1 : t4a1;
                const float4v& x2 = tt ? t4b2 : t4a2;
                float vv[12];
#pragma unroll
                for (int r = 0; r < 4; ++r) {
                    vv[3 * r + 0] = C_NV * (x0[r] + t3[r] * s0);
                    vv[3 * r + 1] = C_NV * (x1[r] + t3[r] * s1);
                    vv[3 * r + 2] = C_NV * (x2[r] + t3[r] * s2);
                }
#pragma unroll
                for (int r2 = 0; r2 < 6; ++r2)
                    pV[tt][r2] = __floats2half2_rn(vv[2 * r2], vv[2 * r2 + 1]);
            }
        }
        __syncthreads();   // protect actL/featL/rcvL before next group's P0a
        havePrev = true;
    }

    // drain last group's payload
    if (havePrev) {
#pragma unroll
        for (int tt = 0; tt < 2; ++tt) {
            if (pValid[tt]) {
                __half2* a2 = agg2 + (long)pR[tt] * 20;
                h2_atomic_add(a2 + lg * 2 + 0, pOS[tt][0]);
                h2_atomic_add(a2 + lg * 2 + 1, pOS[tt][1]);
                if (lg < 2) {
#pragma unroll
                    for (int r2 = 0; r2 < 6; ++r2)
                        h2_atomic_add(a2 + 8 + 6 * lg + r2, pV[tt][r2]);
                }
            }
        }
    }
}

// Read f16 agg from ws, apply gate + residual, write full f32 output row.
__global__ __launch_bounds__(256) void node_kernel2(
    const float* __restrict__ h,
    const float* __restrict__ gw,    // [16][24]
    const float* __restrict__ gb,    // [24]
    const __half2* __restrict__ agg2,
    float*       __restrict__ out)
{
    const int n = blockIdx.x * 256 + threadIdx.x;
    if (n >= N_NODES) return;
    const float* hp = h + (long)n * DIM;
    float* op = out + (long)n * DIM;
    const __half2* ar = agg2 + (long)n * 20;

    float ag[DIM];
#pragma unroll
    for (int i = 0; i < 20; ++i) {
        const float2 f = __half22float2(ar[i]);
        ag[2 * i] = f.x;
        ag[2 * i + 1] = f.y;
    }

    float hsv[MUL0];
#pragma unroll
    for (int u = 0; u < MUL0; ++u) hsv[u] = hp[u];
#pragma unroll
    for (int i = 0; i < MUL0; ++i) op[i] = hsv[i] + ag[i];

#pragma unroll 1
    for (int j = 0; j < 3 * MUL1; ++j) {
        float a = gb[j];
#pragma unroll
        for (int u = 0; u < MUL0; ++u) a = fmaf(hsv[u], gw[u * (3 * MUL1) + j], a);
        const float g = 1.0f / (1.0f + __expf(-a));
        op[MUL0 + j] = fmaf(ag[MUL0 + j], g, hp[MUL0 + j]);
    }
}

extern "C" void kernel_launch(void* const* d_in, const int* in_sizes, int n_in,
                              void* d_out, int out_size, void* d_ws, size_t ws_size,
                              hipStream_t stream)
{
    const float* h    = (const float*)d_in[0];
    const int*   ei   = (const int*)d_in[1];
    const float* evec = (const float*)d_in[2];
    const float* elen = (const float*)d_in[3];
    const float* w1   = (const float*)d_in[4];
    const float* b1   = (const float*)d_in[5];
    const float* w2   = (const float*)d_in[6];
    const float* b2   = (const float*)d_in[7];
    const float* gw   = (const float*)d_in[8];
    const float* gb   = (const float*)d_in[9];
    float* out = (float*)d_out;
    __half2* agg2 = (__half2*)d_ws;   // 50000*40*2 B = 4 MB

    (void)hipFuncSetAttribute((const void*)edge_fused3,
                              hipFuncAttributeMaxDynamicSharedMemorySize,
                              LDS_BYTES);

    (void)hipMemsetAsync(d_ws, 0, (size_t)N_NODES * DIM * sizeof(__half), stream);
    edge_fused3<<<GRID, 512, LDS_BYTES, stream>>>(
        h, ei, evec, elen, w1, b1, w2, b2, agg2);
    node_kernel2<<<(N_NODES + 255) / 256, 256, 0, stream>>>(h, gw, gb, agg2, out);
}